// Round 1
// 671.197 us; speedup vs baseline: 1.0462x; 1.0462x over previous
//
#include <hip/hip_runtime.h>
#include <hip/hip_bf16.h>

#define DEV __device__ __forceinline__

constexpr int NC = 200000;   // clauses
constexpr int NF = 64;       // features
constexpr int NH = 128;      // hidden
constexpr int NS = 512;      // SEL steps

// ---- workspace layout (float units) ----
constexpr int OF_CFG   = 0;                 // int[16]: [0]=float_kind(0=f32,1=bf16), [1]=mask_width(1/2/4 bytes)
constexpr int OF_B1    = 16;                // 128
constexpr int OF_W2K   = OF_B1 + NH;        // 128  (W2 @ key_w)
constexpr int OF_B2K   = OF_W2K + NH;       // 1    (b2 . key_w)
constexpr int OF_MAX   = OF_B2K + 1;        // 1    (flipped-uint global max of logits)
constexpr int OF_ACCE  = 288;               // 512  sum exp(l-M) over passive
constexpr int OF_ACCP  = OF_ACCE + NS;      // 512  sum logits over passive&proof
constexpr int OF_ACCC  = OF_ACCP + NS;      // 512  count passive&proof
constexpr int OF_W1H   = 2048;              // 4096 floats = 8192 bf16 hi, MFMA B-fragment order
constexpr int OF_W1L   = 6144;              // 4096 floats = 8192 bf16 lo
constexpr int OF_LOGIT = 16384;             // 200000
constexpr int OF_E     = OF_LOGIT + NC;     // 200000 exp(l-M)
constexpr int OF_PL    = OF_E + NC;         // 200000 proof? l : 0
constexpr int OF_PC    = OF_PL + NC;        // 200000 proof? 1 : 0
// total = OF_PC + NC = 816384 floats = ~3.2 MB of d_ws

using short8  = __attribute__((ext_vector_type(8))) short;
using floatx4 = __attribute__((ext_vector_type(4))) float;

DEV float bf2f(unsigned short u) { return __uint_as_float(((unsigned)u) << 16); }

DEV float loadF(const void* p, int i, int fk) {
    return fk ? bf2f(((const unsigned short*)p)[i]) : ((const float*)p)[i];
}

// fp32 -> bf16 with round-to-nearest-even (inputs finite)
DEV unsigned short f2bf(float x) {
    unsigned u = __float_as_uint(x);
    unsigned r = ((u >> 16) & 1u) + 0x7FFFu;
    return (unsigned short)((u + r) >> 16);
}

// order-preserving float->uint map for atomicMax
DEV unsigned flipf(float x) {
    unsigned u = __float_as_uint(x);
    return (u & 0x80000000u) ? ~u : (u | 0x80000000u);
}
DEV float unflipf(unsigned u) {
    unsigned b = (u & 0x80000000u) ? (u ^ 0x80000000u) : ~u;
    return __uint_as_float(b);
}

DEV bool okhalf(unsigned h) { return h == 0u || h == 1u || h == 0x3F80u || h == 0x3C00u; }

// ---------------- K0: dtype probe + precompute (incl. W1 bf16 hi/lo in fragment order) ----------------
__global__ void k_probe(const void* features, const void* W1, const void* b1,
                        const void* W2, const void* b2, const void* keyw,
                        const void* sel, float* ws) {
    __shared__ int s_tiny, s_w4, s_w2;
    __shared__ float kw[NH];
    __shared__ float pr[NH];
    int tx = threadIdx.x;
    if (tx == 0) { s_tiny = 0; s_w4 = 1; s_w2 = 1; }
    __syncthreads();
    {
        const unsigned short* u = (const unsigned short*)features;
        unsigned e = (u[tx] >> 7) & 0xFFu;     // exponent field as-if bf16
        if (e < 100u) atomicAdd(&s_tiny, 1);   // fp32 low-halves: ~39% tiny; bf16 N(0,1): ~0
        const unsigned* wrd = (const unsigned*)sel;
        unsigned v = wrd[tx];
        if (!(v == 0u || v == 1u || v == 0x3F800000u)) atomicAnd(&s_w4, 0);
        if (!(okhalf(v & 0xFFFFu) && okhalf(v >> 16))) atomicAnd(&s_w2, 0);
    }
    __syncthreads();
    int fk = (s_tiny >= 8) ? 0 : 1;                   // 0=fp32, 1=bf16
    int mw = s_w4 ? 4 : (s_w2 ? 2 : 1);               // mask element bytes
    if (tx == 0) { ((int*)ws)[0] = fk; ((int*)ws)[1] = mw; }
    if (tx < NH) kw[tx] = loadF(keyw, tx, fk);
    if (tx < NH) ws[OF_B1 + tx] = loadF(b1, tx, fk);
    // W1 -> bf16 hi/lo, stored in exact MFMA B-fragment order:
    // i = ((c*2+ks)*64 + lane)*8 + j  <->  W1[k][col], k = ks*32 + (lane>>4)*8 + j, col = c*16 + (lane&15)
    unsigned short* w1h = (unsigned short*)(ws + OF_W1H);
    unsigned short* w1l = (unsigned short*)(ws + OF_W1L);
    for (int i = tx; i < NF * NH; i += blockDim.x) {
        int j    = i & 7;
        int lane = (i >> 3) & 63;
        int ks   = (i >> 9) & 1;
        int c    = i >> 10;
        int k    = ks * 32 + ((lane >> 4) << 3) + j;
        int col  = c * 16 + (lane & 15);
        if (fk) {
            w1h[i] = ((const unsigned short*)W1)[k * NH + col];
            w1l[i] = 0;
        } else {
            float x = ((const float*)W1)[k * NH + col];
            unsigned short h = f2bf(x);
            w1h[i] = h;
            w1l[i] = f2bf(x - __uint_as_float(((unsigned)h) << 16));
        }
    }
    __syncthreads();
    if (tx < NH) {
        float s = 0.f;
        for (int k = 0; k < NH; k++) s += loadF(W2, tx * NH + k, fk) * kw[k];
        ws[OF_W2K + tx] = s;
        pr[tx] = loadF(b2, tx, fk) * kw[tx];
    }
    __syncthreads();
    if (tx == 0) {
        float s = 0.f;
        for (int k = 0; k < NH; k++) s += pr[k];
        ws[OF_B2K] = s;
        ((unsigned*)ws)[OF_MAX] = 0u;  // flipped -inf sentinel
    }
    for (int i = tx; i < 3 * NS; i += blockDim.x) ws[OF_ACCE + i] = 0.f;
}

// ---------------- K1: logits via bf16 MFMA with hi/lo error compensation ----------------
// Per block: 128 rows. Per wave: 32 rows (2 row-tiles of 16), all 128 hidden cols (8 col-tiles).
// hi/lo split keeps hi*hi + hi*lo + lo*hi (drops lo*lo) -> ~1e-4 abs logit error.
// Operand mapping (m89/m92-verified): A frag: row=lane&15, k=(lane>>4)*8+j;
// B frag: col=lane&15, k=(lane>>4)*8+j; C: row=(lane>>4)*4+reg, col=lane&15.
__global__ __launch_bounds__(256) void k_logits(const void* __restrict__ features,
                                                const float* __restrict__ ws,
                                                float* __restrict__ logits,
                                                unsigned* __restrict__ maxp) {
    __shared__ float sred[4];
    const int tx = threadIdx.x, w = tx >> 6, l = tx & 63;
    const int fk = ((const int*)ws)[0];
    const float b2k = ws[OF_B2K];
    const int rbase = blockIdx.x * 128 + w * 32;
    const int lrow = l & 15;
    const int lk = (l >> 4) << 3;   // k offset: 0,8,16,24

    short8 ah[2][2], al[2][2];
    if (fk) {
        const unsigned short* f = (const unsigned short*)features;
        #pragma unroll
        for (int rt = 0; rt < 2; rt++) {
            int row = rbase + rt * 16 + lrow; if (row > NC - 1) row = NC - 1;
            #pragma unroll
            for (int ks = 0; ks < 2; ks++)
                ah[rt][ks] = *(const short8*)(f + (size_t)row * NF + ks * 32 + lk);
        }
    } else {
        const float* f = (const float*)features;
        #pragma unroll
        for (int rt = 0; rt < 2; rt++) {
            int row = rbase + rt * 16 + lrow; if (row > NC - 1) row = NC - 1;
            #pragma unroll
            for (int ks = 0; ks < 2; ks++) {
                const float* p = f + (size_t)row * NF + ks * 32 + lk;
                float4 v0 = *(const float4*)p;
                float4 v1 = *(const float4*)(p + 4);
                float xs[8] = {v0.x, v0.y, v0.z, v0.w, v1.x, v1.y, v1.z, v1.w};
                #pragma unroll
                for (int j = 0; j < 8; j++) {
                    unsigned short h = f2bf(xs[j]);
                    ah[rt][ks][j] = (short)h;
                    al[rt][ks][j] = (short)f2bf(xs[j] - __uint_as_float(((unsigned)h) << 16));
                }
            }
        }
    }

    const short8* w1h = (const short8*)(ws + OF_W1H);
    const short8* w1l = (const short8*)(ws + OF_W1L);
    float pr[2][4] = {{0.f, 0.f, 0.f, 0.f}, {0.f, 0.f, 0.f, 0.f}};

    #pragma unroll 2
    for (int c = 0; c < 8; c++) {
        short8 bh0 = w1h[(c * 2 + 0) * 64 + l];
        short8 bh1 = w1h[(c * 2 + 1) * 64 + l];
        float b1v = ws[OF_B1 + c * 16 + lrow];   // bias for col = c*16 + (lane&15)
        float wkv = ws[OF_W2K + c * 16 + lrow];  // w2k for same col
        if (fk) {
            #pragma unroll
            for (int rt = 0; rt < 2; rt++) {
                floatx4 acc = {0.f, 0.f, 0.f, 0.f};
                acc = __builtin_amdgcn_mfma_f32_16x16x32_bf16(ah[rt][0], bh0, acc, 0, 0, 0);
                acc = __builtin_amdgcn_mfma_f32_16x16x32_bf16(ah[rt][1], bh1, acc, 0, 0, 0);
                #pragma unroll
                for (int r = 0; r < 4; r++) pr[rt][r] += fmaxf(acc[r] + b1v, 0.f) * wkv;
            }
        } else {
            short8 bl0 = w1l[(c * 2 + 0) * 64 + l];
            short8 bl1 = w1l[(c * 2 + 1) * 64 + l];
            #pragma unroll
            for (int rt = 0; rt < 2; rt++) {
                floatx4 acc = {0.f, 0.f, 0.f, 0.f};
                acc = __builtin_amdgcn_mfma_f32_16x16x32_bf16(ah[rt][0], bh0, acc, 0, 0, 0);
                acc = __builtin_amdgcn_mfma_f32_16x16x32_bf16(ah[rt][1], bh1, acc, 0, 0, 0);
                acc = __builtin_amdgcn_mfma_f32_16x16x32_bf16(ah[rt][0], bl0, acc, 0, 0, 0);
                acc = __builtin_amdgcn_mfma_f32_16x16x32_bf16(ah[rt][1], bl1, acc, 0, 0, 0);
                acc = __builtin_amdgcn_mfma_f32_16x16x32_bf16(al[rt][0], bh0, acc, 0, 0, 0);
                acc = __builtin_amdgcn_mfma_f32_16x16x32_bf16(al[rt][1], bh1, acc, 0, 0, 0);
                #pragma unroll
                for (int r = 0; r < 4; r++) pr[rt][r] += fmaxf(acc[r] + b1v, 0.f) * wkv;
            }
        }
    }

    // butterfly-sum over the 16 lanes sharing a row-group (col dimension); all lanes get the total
    float m = -3.0e38f;
    #pragma unroll
    for (int rt = 0; rt < 2; rt++) {
        #pragma unroll
        for (int r = 0; r < 4; r++) {
            float v = pr[rt][r];
            v += __shfl_xor(v, 1, 64);
            v += __shfl_xor(v, 2, 64);
            v += __shfl_xor(v, 4, 64);
            v += __shfl_xor(v, 8, 64);
            v += b2k;
            int row = rbase + rt * 16 + (l >> 4) * 4 + r;
            if (row < NC) {
                m = fmaxf(m, v);
                if (lrow == 0) logits[row] = v;
            }
        }
    }
    m = fmaxf(m, __shfl_xor(m, 16, 64));
    m = fmaxf(m, __shfl_xor(m, 32, 64));
    if (l == 0) sred[w] = m;
    __syncthreads();
    if (tx == 0) {
        m = fmaxf(fmaxf(sred[0], sred[1]), fmaxf(sred[2], sred[3]));
        atomicMax(maxp, flipf(m));
    }
}

// ---------------- K2: e = exp(l - M), proof-gated logits / counts ----------------
__global__ void k_prep(const void* proof, float* ws) {
    int n = blockIdx.x * 256 + threadIdx.x;
    if (n >= NC) return;
    int mw = ((const int*)ws)[1];
    float M = unflipf(((const unsigned*)ws)[OF_MAX]);
    float l = ws[OF_LOGIT + n];
    ws[OF_E + n] = __expf(l - M);
    bool pf;
    if (mw == 1)      pf = ((const unsigned char*)proof)[n] != 0;
    else if (mw == 2) pf = ((const unsigned short*)proof)[n] != 0;
    else              pf = ((const unsigned*)proof)[n] != 0;
    ws[OF_PL + n] = pf ? l : 0.f;
    ws[OF_PC + n] = pf ? 1.f : 0.f;
}

// ---------------- K3: the big masked accumulation over sel_mask ----------------
constexpr int NT_N = 16;            // n per thread (register-resident e/pl/pc)
constexpr int BL_N = 256 * NT_N;    // 4096 n per block
constexpr int SG = 32;              // s per block

template<int MW>
DEV void bloop(const void* sel, int s0, int baddr,
               const float (&e)[NT_N], const float (&pl)[NT_N], const float (&pc)[NT_N],
               float* ws) {
    for (int si = 0; si < SG; si++) {
        int s = s0 + si;
        size_t off = (size_t)s * NC + (size_t)baddr;
        float m[NT_N];
        if (MW == 1) {
            uint4 w = *(const uint4*)((const unsigned char*)sel + off);
            unsigned v[4] = {w.x, w.y, w.z, w.w};
            #pragma unroll
            for (int q = 0; q < 4; q++)
                #pragma unroll
                for (int b = 0; b < 4; b++)
                    m[q * 4 + b] = ((v[q] >> (8 * b)) & 0xFFu) ? 1.f : 0.f;
        } else if (MW == 2) {
            const uint4* p = (const uint4*)((const unsigned short*)sel + off);
            #pragma unroll
            for (int h = 0; h < 2; h++) {
                uint4 w = p[h];
                unsigned v[4] = {w.x, w.y, w.z, w.w};
                #pragma unroll
                for (int q = 0; q < 4; q++) {
                    m[h * 8 + q * 2 + 0] = (v[q] & 0xFFFFu) ? 1.f : 0.f;
                    m[h * 8 + q * 2 + 1] = (v[q] >> 16) ? 1.f : 0.f;
                }
            }
        } else {
            const uint4* p = (const uint4*)((const unsigned*)sel + off);
            #pragma unroll
            for (int q = 0; q < 4; q++) {
                uint4 w = p[q];
                m[q * 4 + 0] = w.x ? 1.f : 0.f; m[q * 4 + 1] = w.y ? 1.f : 0.f;
                m[q * 4 + 2] = w.z ? 1.f : 0.f; m[q * 4 + 3] = w.w ? 1.f : 0.f;
            }
        }
        float se = 0.f, sp = 0.f, sc = 0.f;
        #pragma unroll
        for (int i = 0; i < NT_N; i++) {
            se += m[i] * e[i]; sp += m[i] * pl[i]; sc += m[i] * pc[i];
        }
        #pragma unroll
        for (int k = 1; k < 64; k <<= 1) {
            se += __shfl_xor(se, k, 64);
            sp += __shfl_xor(sp, k, 64);
            sc += __shfl_xor(sc, k, 64);
        }
        if ((threadIdx.x & 63) == 0) {
            atomicAdd(&ws[OF_ACCE + s], se);
            atomicAdd(&ws[OF_ACCP + s], sp);
            atomicAdd(&ws[OF_ACCC + s], sc);
        }
    }
}

__global__ __launch_bounds__(256) void k_phaseB(const void* sel, float* ws) {
    int tx = threadIdx.x;
    int base = blockIdx.x * BL_N + tx * NT_N;
    int s0 = blockIdx.y * SG;
    bool active = base < NC;                 // NC % 16 == 0, so active threads are fully valid
    int baddr = active ? base : 0;
    float e[NT_N], pl[NT_N], pc[NT_N];
    #pragma unroll
    for (int q = 0; q < 4; q++) {
        float4 ve = active ? ((const float4*)&ws[OF_E + baddr])[q]  : make_float4(0, 0, 0, 0);
        float4 vp = active ? ((const float4*)&ws[OF_PL + baddr])[q] : make_float4(0, 0, 0, 0);
        float4 vc = active ? ((const float4*)&ws[OF_PC + baddr])[q] : make_float4(0, 0, 0, 0);
        e[q * 4 + 0] = ve.x; e[q * 4 + 1] = ve.y; e[q * 4 + 2] = ve.z; e[q * 4 + 3] = ve.w;
        pl[q * 4 + 0] = vp.x; pl[q * 4 + 1] = vp.y; pl[q * 4 + 2] = vp.z; pl[q * 4 + 3] = vp.w;
        pc[q * 4 + 0] = vc.x; pc[q * 4 + 1] = vc.y; pc[q * 4 + 2] = vc.z; pc[q * 4 + 3] = vc.w;
    }
    int mw = ((const int*)ws)[1];
    if (mw == 1)      bloop<1>(sel, s0, baddr, e, pl, pc, ws);
    else if (mw == 2) bloop<2>(sel, s0, baddr, e, pl, pc, ws);
    else              bloop<4>(sel, s0, baddr, e, pl, pc, ws);
}

// ---------------- K4: per-step loss + mean, cast to output dtype ----------------
__global__ void k_final(float* ws, void* out) {
    __shared__ float sred[256];
    int tx = threadIdx.x;
    float M = unflipf(((const unsigned*)ws)[OF_MAX]);
    float sum = 0.f;
    for (int s = tx; s < NS; s += 256) {
        float lse = M + logf(ws[OF_ACCE + s]);
        sum += lse - ws[OF_ACCP + s] / ws[OF_ACCC + s];
    }
    sred[tx] = sum;
    __syncthreads();
    for (int k = 128; k > 0; k >>= 1) {
        if (tx < k) sred[tx] += sred[tx + k];
        __syncthreads();
    }
    if (tx == 0) {
        float loss = sred[0] / (float)NS;
        int fk = ((const int*)ws)[0];
        if (fk) ((__hip_bfloat16*)out)[0] = __float2bfloat16(loss);
        else    ((float*)out)[0] = loss;
    }
}

extern "C" void kernel_launch(void* const* d_in, const int* in_sizes, int n_in,
                              void* d_out, int out_size, void* d_ws, size_t ws_size,
                              hipStream_t stream) {
    const void* features = d_in[0];
    const void* W1   = d_in[1];
    const void* b1   = d_in[2];
    const void* W2   = d_in[3];
    const void* b2   = d_in[4];
    const void* keyw = d_in[5];
    const void* sel  = d_in[6];
    const void* proof = d_in[7];
    float* ws = (float*)d_ws;

    k_probe<<<1, 256, 0, stream>>>(features, W1, b1, W2, b2, keyw, sel, ws);
    int nblkL = (NC + 127) / 128;
    k_logits<<<nblkL, 256, 0, stream>>>(features, ws, ws + OF_LOGIT, (unsigned*)ws + OF_MAX);
    int nblk = (NC + 255) / 256;
    k_prep<<<nblk, 256, 0, stream>>>(proof, ws);
    dim3 gB((NC + BL_N - 1) / BL_N, NS / SG);
    k_phaseB<<<gB, 256, 0, stream>>>(sel, ws);
    k_final<<<1, 256, 0, stream>>>(ws, d_out);
}

// Round 2
// 657.570 us; speedup vs baseline: 1.0679x; 1.0207x over previous
//
#include <hip/hip_runtime.h>
#include <hip/hip_bf16.h>

#define DEV __device__ __forceinline__

constexpr int NC = 200000;   // clauses
constexpr int NF = 64;       // features
constexpr int NH = 128;      // hidden
constexpr int NS = 512;      // SEL steps

// ---- workspace layout (float units) ----
constexpr int OF_CFG   = 0;                 // int[16]: [0]=float_kind(0=f32,1=bf16), [1]=mask_width(1/2/4 bytes)
constexpr int OF_B1    = 16;                // 128
constexpr int OF_W2K   = OF_B1 + NH;        // 128  (W2 @ key_w)
constexpr int OF_B2K   = OF_W2K + NH;       // 1    (b2 . key_w)
constexpr int OF_MAX   = OF_B2K + 1;        // 1    (flipped-uint global max of logits)
constexpr int OF_ACCE  = 288;               // 512  sum exp(l-M) over passive
constexpr int OF_ACCP  = OF_ACCE + NS;      // 512  sum logits over passive&proof
constexpr int OF_ACCC  = OF_ACCP + NS;      // 512  count passive&proof
constexpr int OF_W1H   = 2048;              // 4096 floats = 8192 bf16 hi, MFMA B-fragment order
constexpr int OF_W1L   = 6144;              // 4096 floats = 8192 bf16 lo
constexpr int OF_LOGIT = 16384;             // 200000
// total = OF_LOGIT + NC = ~0.9 MB of d_ws

using short8  = __attribute__((ext_vector_type(8))) short;
using floatx4 = __attribute__((ext_vector_type(4))) float;

DEV float bf2f(unsigned short u) { return __uint_as_float(((unsigned)u) << 16); }

DEV float loadF(const void* p, int i, int fk) {
    return fk ? bf2f(((const unsigned short*)p)[i]) : ((const float*)p)[i];
}

// fp32 -> bf16 with round-to-nearest-even (inputs finite)
DEV unsigned short f2bf(float x) {
    unsigned u = __float_as_uint(x);
    unsigned r = ((u >> 16) & 1u) + 0x7FFFu;
    return (unsigned short)((u + r) >> 16);
}

// order-preserving float->uint map for atomicMax
DEV unsigned flipf(float x) {
    unsigned u = __float_as_uint(x);
    return (u & 0x80000000u) ? ~u : (u | 0x80000000u);
}
DEV float unflipf(unsigned u) {
    unsigned b = (u & 0x80000000u) ? (u ^ 0x80000000u) : ~u;
    return __uint_as_float(b);
}

DEV bool okhalf(unsigned h) { return h == 0u || h == 1u || h == 0x3F80u || h == 0x3C00u; }

// ---------------- K0: dtype probe + precompute (incl. W1 bf16 hi/lo in fragment order) ----------------
__global__ void k_probe(const void* features, const void* W1, const void* b1,
                        const void* W2, const void* b2, const void* keyw,
                        const void* sel, float* ws) {
    __shared__ int s_tiny, s_w4, s_w2;
    __shared__ float kw[NH];
    __shared__ float pr[NH];
    int tx = threadIdx.x;
    if (tx == 0) { s_tiny = 0; s_w4 = 1; s_w2 = 1; }
    __syncthreads();
    {
        const unsigned short* u = (const unsigned short*)features;
        unsigned e = (u[tx] >> 7) & 0xFFu;     // exponent field as-if bf16
        if (e < 100u) atomicAdd(&s_tiny, 1);   // fp32 low-halves: ~39% tiny; bf16 N(0,1): ~0
        const unsigned* wrd = (const unsigned*)sel;
        unsigned v = wrd[tx];
        if (!(v == 0u || v == 1u || v == 0x3F800000u)) atomicAnd(&s_w4, 0);
        if (!(okhalf(v & 0xFFFFu) && okhalf(v >> 16))) atomicAnd(&s_w2, 0);
    }
    __syncthreads();
    int fk = (s_tiny >= 8) ? 0 : 1;                   // 0=fp32, 1=bf16
    int mw = s_w4 ? 4 : (s_w2 ? 2 : 1);               // mask element bytes
    if (tx == 0) { ((int*)ws)[0] = fk; ((int*)ws)[1] = mw; }
    if (tx < NH) kw[tx] = loadF(keyw, tx, fk);
    if (tx < NH) ws[OF_B1 + tx] = loadF(b1, tx, fk);
    // W1 -> bf16 hi/lo, stored in exact MFMA B-fragment order:
    // i = ((c*2+ks)*64 + lane)*8 + j  <->  W1[k][col], k = ks*32 + (lane>>4)*8 + j, col = c*16 + (lane&15)
    unsigned short* w1h = (unsigned short*)(ws + OF_W1H);
    unsigned short* w1l = (unsigned short*)(ws + OF_W1L);
    for (int i = tx; i < NF * NH; i += blockDim.x) {
        int j    = i & 7;
        int lane = (i >> 3) & 63;
        int ks   = (i >> 9) & 1;
        int c    = i >> 10;
        int k    = ks * 32 + ((lane >> 4) << 3) + j;
        int col  = c * 16 + (lane & 15);
        if (fk) {
            w1h[i] = ((const unsigned short*)W1)[k * NH + col];
            w1l[i] = 0;
        } else {
            float x = ((const float*)W1)[k * NH + col];
            unsigned short h = f2bf(x);
            w1h[i] = h;
            w1l[i] = f2bf(x - __uint_as_float(((unsigned)h) << 16));
        }
    }
    __syncthreads();
    if (tx < NH) {
        float s = 0.f;
        for (int k = 0; k < NH; k++) s += loadF(W2, tx * NH + k, fk) * kw[k];
        ws[OF_W2K + tx] = s;
        pr[tx] = loadF(b2, tx, fk) * kw[tx];
    }
    __syncthreads();
    if (tx == 0) {
        float s = 0.f;
        for (int k = 0; k < NH; k++) s += pr[k];
        ws[OF_B2K] = s;
        ((unsigned*)ws)[OF_MAX] = 0u;  // flipped -inf sentinel
    }
    for (int i = tx; i < 3 * NS; i += blockDim.x) ws[OF_ACCE + i] = 0.f;
}

// ---------------- K1: logits via bf16 MFMA with hi/lo error compensation ----------------
// Per block: 128 rows. Per wave: 32 rows (2 row-tiles of 16), all 128 hidden cols (8 col-tiles).
// hi/lo split keeps hi*hi + hi*lo + lo*hi (drops lo*lo) -> ~1e-4 abs logit error.
// Operand mapping (m89/m92-verified): A frag: row=lane&15, k=(lane>>4)*8+j;
// B frag: col=lane&15, k=(lane>>4)*8+j; C: row=(lane>>4)*4+reg, col=lane&15.
__global__ __launch_bounds__(256) void k_logits(const void* __restrict__ features,
                                                const float* __restrict__ ws,
                                                float* __restrict__ logits,
                                                unsigned* __restrict__ maxp) {
    __shared__ float sred[4];
    const int tx = threadIdx.x, w = tx >> 6, l = tx & 63;
    const int fk = ((const int*)ws)[0];
    const float b2k = ws[OF_B2K];
    const int rbase = blockIdx.x * 128 + w * 32;
    const int lrow = l & 15;
    const int lk = (l >> 4) << 3;   // k offset: 0,8,16,24

    short8 ah[2][2], al[2][2];
    if (fk) {
        const unsigned short* f = (const unsigned short*)features;
        #pragma unroll
        for (int rt = 0; rt < 2; rt++) {
            int row = rbase + rt * 16 + lrow; if (row > NC - 1) row = NC - 1;
            #pragma unroll
            for (int ks = 0; ks < 2; ks++)
                ah[rt][ks] = *(const short8*)(f + (size_t)row * NF + ks * 32 + lk);
        }
    } else {
        const float* f = (const float*)features;
        #pragma unroll
        for (int rt = 0; rt < 2; rt++) {
            int row = rbase + rt * 16 + lrow; if (row > NC - 1) row = NC - 1;
            #pragma unroll
            for (int ks = 0; ks < 2; ks++) {
                const float* p = f + (size_t)row * NF + ks * 32 + lk;
                float4 v0 = *(const float4*)p;
                float4 v1 = *(const float4*)(p + 4);
                float xs[8] = {v0.x, v0.y, v0.z, v0.w, v1.x, v1.y, v1.z, v1.w};
                #pragma unroll
                for (int j = 0; j < 8; j++) {
                    unsigned short h = f2bf(xs[j]);
                    ah[rt][ks][j] = (short)h;
                    al[rt][ks][j] = (short)f2bf(xs[j] - __uint_as_float(((unsigned)h) << 16));
                }
            }
        }
    }

    const short8* w1h = (const short8*)(ws + OF_W1H);
    const short8* w1l = (const short8*)(ws + OF_W1L);
    float pr[2][4] = {{0.f, 0.f, 0.f, 0.f}, {0.f, 0.f, 0.f, 0.f}};

    #pragma unroll 2
    for (int c = 0; c < 8; c++) {
        short8 bh0 = w1h[(c * 2 + 0) * 64 + l];
        short8 bh1 = w1h[(c * 2 + 1) * 64 + l];
        float b1v = ws[OF_B1 + c * 16 + lrow];   // bias for col = c*16 + (lane&15)
        float wkv = ws[OF_W2K + c * 16 + lrow];  // w2k for same col
        if (fk) {
            #pragma unroll
            for (int rt = 0; rt < 2; rt++) {
                floatx4 acc = {0.f, 0.f, 0.f, 0.f};
                acc = __builtin_amdgcn_mfma_f32_16x16x32_bf16(ah[rt][0], bh0, acc, 0, 0, 0);
                acc = __builtin_amdgcn_mfma_f32_16x16x32_bf16(ah[rt][1], bh1, acc, 0, 0, 0);
                #pragma unroll
                for (int r = 0; r < 4; r++) pr[rt][r] += fmaxf(acc[r] + b1v, 0.f) * wkv;
            }
        } else {
            short8 bl0 = w1l[(c * 2 + 0) * 64 + l];
            short8 bl1 = w1l[(c * 2 + 1) * 64 + l];
            #pragma unroll
            for (int rt = 0; rt < 2; rt++) {
                floatx4 acc = {0.f, 0.f, 0.f, 0.f};
                acc = __builtin_amdgcn_mfma_f32_16x16x32_bf16(ah[rt][0], bh0, acc, 0, 0, 0);
                acc = __builtin_amdgcn_mfma_f32_16x16x32_bf16(ah[rt][1], bh1, acc, 0, 0, 0);
                acc = __builtin_amdgcn_mfma_f32_16x16x32_bf16(ah[rt][0], bl0, acc, 0, 0, 0);
                acc = __builtin_amdgcn_mfma_f32_16x16x32_bf16(ah[rt][1], bl1, acc, 0, 0, 0);
                acc = __builtin_amdgcn_mfma_f32_16x16x32_bf16(al[rt][0], bh0, acc, 0, 0, 0);
                acc = __builtin_amdgcn_mfma_f32_16x16x32_bf16(al[rt][1], bh1, acc, 0, 0, 0);
                #pragma unroll
                for (int r = 0; r < 4; r++) pr[rt][r] += fmaxf(acc[r] + b1v, 0.f) * wkv;
            }
        }
    }

    // butterfly-sum over the 16 lanes sharing a row-group (col dimension); all lanes get the total
    float m = -3.0e38f;
    #pragma unroll
    for (int rt = 0; rt < 2; rt++) {
        #pragma unroll
        for (int r = 0; r < 4; r++) {
            float v = pr[rt][r];
            v += __shfl_xor(v, 1, 64);
            v += __shfl_xor(v, 2, 64);
            v += __shfl_xor(v, 4, 64);
            v += __shfl_xor(v, 8, 64);
            v += b2k;
            int row = rbase + rt * 16 + (l >> 4) * 4 + r;
            if (row < NC) {
                m = fmaxf(m, v);
                if (lrow == 0) logits[row] = v;
            }
        }
    }
    m = fmaxf(m, __shfl_xor(m, 16, 64));
    m = fmaxf(m, __shfl_xor(m, 32, 64));
    if (l == 0) sred[w] = m;
    __syncthreads();
    if (tx == 0) {
        m = fmaxf(fmaxf(sred[0], sred[1]), fmaxf(sred[2], sred[3]));
        atomicMax(maxp, flipf(m));
    }
}

// ---------------- K2: the big masked accumulation over sel_mask ----------------
// (k_prep folded in: e/pl/pc are computed from logits+proof in the block prologue.)
constexpr int NT_N = 16;            // n per thread (register-resident e/pl/pc)
constexpr int BL_N = 256 * NT_N;    // 4096 n per block
constexpr int SG = 32;              // s per block

template<int MW>
DEV void prologue(const float* __restrict__ ws, const void* __restrict__ proof,
                  int baddr, bool active, float M,
                  float (&e)[NT_N], float (&pl)[NT_N], float (&pc)[NT_N]) {
    if (!active) {
        #pragma unroll
        for (int i = 0; i < NT_N; i++) { e[i] = 0.f; pl[i] = 0.f; pc[i] = 0.f; }
        return;
    }
    float lv[NT_N];
    #pragma unroll
    for (int q = 0; q < 4; q++) {
        float4 v = ((const float4*)(ws + OF_LOGIT + baddr))[q];
        lv[q * 4 + 0] = v.x; lv[q * 4 + 1] = v.y; lv[q * 4 + 2] = v.z; lv[q * 4 + 3] = v.w;
    }
    unsigned pm[NT_N];
    if (MW == 1) {
        uint4 w = *(const uint4*)((const unsigned char*)proof + baddr);
        unsigned v[4] = {w.x, w.y, w.z, w.w};
        #pragma unroll
        for (int q = 0; q < 4; q++)
            #pragma unroll
            for (int b = 0; b < 4; b++)
                pm[q * 4 + b] = (v[q] >> (8 * b)) & 0xFFu;
    } else if (MW == 2) {
        const uint4* p = (const uint4*)((const unsigned short*)proof + baddr);
        #pragma unroll
        for (int h = 0; h < 2; h++) {
            uint4 w = p[h];
            unsigned v[4] = {w.x, w.y, w.z, w.w};
            #pragma unroll
            for (int q = 0; q < 4; q++) {
                pm[h * 8 + q * 2 + 0] = v[q] & 0xFFFFu;
                pm[h * 8 + q * 2 + 1] = v[q] >> 16;
            }
        }
    } else {
        const uint4* p = (const uint4*)((const unsigned*)proof + baddr);
        #pragma unroll
        for (int q = 0; q < 4; q++) {
            uint4 w = p[q];
            pm[q * 4 + 0] = w.x; pm[q * 4 + 1] = w.y;
            pm[q * 4 + 2] = w.z; pm[q * 4 + 3] = w.w;
        }
    }
    #pragma unroll
    for (int i = 0; i < NT_N; i++) {
        e[i]  = __expf(lv[i] - M);
        pl[i] = pm[i] ? lv[i] : 0.f;
        pc[i] = pm[i] ? 1.f : 0.f;
    }
}

template<int MW>
DEV void bloop(const void* sel, int s0, int baddr,
               const float (&e)[NT_N], const float (&pl)[NT_N], const float (&pc)[NT_N],
               float* ws) {
    for (int si = 0; si < SG; si++) {
        int s = s0 + si;
        size_t off = (size_t)s * NC + (size_t)baddr;
        float m[NT_N];
        if (MW == 1) {
            uint4 w = *(const uint4*)((const unsigned char*)sel + off);
            unsigned v[4] = {w.x, w.y, w.z, w.w};
            #pragma unroll
            for (int q = 0; q < 4; q++)
                #pragma unroll
                for (int b = 0; b < 4; b++)
                    m[q * 4 + b] = ((v[q] >> (8 * b)) & 0xFFu) ? 1.f : 0.f;
        } else if (MW == 2) {
            const uint4* p = (const uint4*)((const unsigned short*)sel + off);
            #pragma unroll
            for (int h = 0; h < 2; h++) {
                uint4 w = p[h];
                unsigned v[4] = {w.x, w.y, w.z, w.w};
                #pragma unroll
                for (int q = 0; q < 4; q++) {
                    m[h * 8 + q * 2 + 0] = (v[q] & 0xFFFFu) ? 1.f : 0.f;
                    m[h * 8 + q * 2 + 1] = (v[q] >> 16) ? 1.f : 0.f;
                }
            }
        } else {
            const uint4* p = (const uint4*)((const unsigned*)sel + off);
            #pragma unroll
            for (int q = 0; q < 4; q++) {
                uint4 w = p[q];
                m[q * 4 + 0] = w.x ? 1.f : 0.f; m[q * 4 + 1] = w.y ? 1.f : 0.f;
                m[q * 4 + 2] = w.z ? 1.f : 0.f; m[q * 4 + 3] = w.w ? 1.f : 0.f;
            }
        }
        float se = 0.f, sp = 0.f, sc = 0.f;
        #pragma unroll
        for (int i = 0; i < NT_N; i++) {
            se += m[i] * e[i]; sp += m[i] * pl[i]; sc += m[i] * pc[i];
        }
        #pragma unroll
        for (int k = 1; k < 64; k <<= 1) {
            se += __shfl_xor(se, k, 64);
            sp += __shfl_xor(sp, k, 64);
            sc += __shfl_xor(sc, k, 64);
        }
        if ((threadIdx.x & 63) == 0) {
            atomicAdd(&ws[OF_ACCE + s], se);
            atomicAdd(&ws[OF_ACCP + s], sp);
            atomicAdd(&ws[OF_ACCC + s], sc);
        }
    }
}

__global__ __launch_bounds__(256) void k_phaseB(const void* sel, const void* proof, float* ws) {
    int tx = threadIdx.x;
    int base = blockIdx.x * BL_N + tx * NT_N;
    int s0 = blockIdx.y * SG;
    bool active = base < NC;                 // NC % 16 == 0, so active threads are fully valid
    int baddr = active ? base : 0;
    int mw = ((const int*)ws)[1];
    float M = unflipf(((const unsigned*)ws)[OF_MAX]);
    float e[NT_N], pl[NT_N], pc[NT_N];
    if (mw == 1) {
        prologue<1>(ws, proof, baddr, active, M, e, pl, pc);
        bloop<1>(sel, s0, baddr, e, pl, pc, ws);
    } else if (mw == 2) {
        prologue<2>(ws, proof, baddr, active, M, e, pl, pc);
        bloop<2>(sel, s0, baddr, e, pl, pc, ws);
    } else {
        prologue<4>(ws, proof, baddr, active, M, e, pl, pc);
        bloop<4>(sel, s0, baddr, e, pl, pc, ws);
    }
}

// ---------------- K3: per-step loss + mean, cast to output dtype ----------------
__global__ void k_final(float* ws, void* out) {
    __shared__ float sred[256];
    int tx = threadIdx.x;
    float M = unflipf(((const unsigned*)ws)[OF_MAX]);
    float sum = 0.f;
    for (int s = tx; s < NS; s += 256) {
        float lse = M + logf(ws[OF_ACCE + s]);
        sum += lse - ws[OF_ACCP + s] / ws[OF_ACCC + s];
    }
    sred[tx] = sum;
    __syncthreads();
    for (int k = 128; k > 0; k >>= 1) {
        if (tx < k) sred[tx] += sred[tx + k];
        __syncthreads();
    }
    if (tx == 0) {
        float loss = sred[0] / (float)NS;
        int fk = ((const int*)ws)[0];
        if (fk) ((__hip_bfloat16*)out)[0] = __float2bfloat16(loss);
        else    ((float*)out)[0] = loss;
    }
}

extern "C" void kernel_launch(void* const* d_in, const int* in_sizes, int n_in,
                              void* d_out, int out_size, void* d_ws, size_t ws_size,
                              hipStream_t stream) {
    const void* features = d_in[0];
    const void* W1   = d_in[1];
    const void* b1   = d_in[2];
    const void* W2   = d_in[3];
    const void* b2   = d_in[4];
    const void* keyw = d_in[5];
    const void* sel  = d_in[6];
    const void* proof = d_in[7];
    float* ws = (float*)d_ws;

    k_probe<<<1, 256, 0, stream>>>(features, W1, b1, W2, b2, keyw, sel, ws);
    int nblkL = (NC + 127) / 128;
    k_logits<<<nblkL, 256, 0, stream>>>(features, ws, ws + OF_LOGIT, (unsigned*)ws + OF_MAX);
    dim3 gB((NC + BL_N - 1) / BL_N, NS / SG);
    k_phaseB<<<gB, 256, 0, stream>>>(sel, proof, ws);
    k_final<<<1, 256, 0, stream>>>(ws, d_out);
}